// Round 6
// baseline (480.075 us; speedup 1.0000x reference)
//
#include <hip/hip_runtime.h>
#include <hip/hip_bf16.h>
#include <math.h>

#define DIM 512
#define NHEAD 8
#define HD 64
#define BATCH 2
#define SEQ 4096
#define CTXLEN 77
#define NTOK (BATCH*SEQ)     // 8192
#define NCTX (BATCH*CTXLEN)  // 154

typedef __hip_bfloat16 bf16;
typedef __attribute__((ext_vector_type(8))) short bf8_t;   // 8 bf16 (4 VGPRs)
typedef __attribute__((ext_vector_type(4))) float f4_t;    // 4 fp32 acc

__device__ __forceinline__ float b2f(bf16 v){ return __bfloat162float(v); }
__device__ __forceinline__ bf16  f2b(float v){ return __float2bfloat16(v); }
// fast bf16 pair pack: round-half-up + one v_perm_b32; low element = a, high = b
__device__ __forceinline__ unsigned int packbf2(float a, float b){
    unsigned int au = __float_as_uint(a) + 0x8000u;
    unsigned int bu = __float_as_uint(b) + 0x8000u;
    return __builtin_amdgcn_perm(bu, au, 0x07060302u);
}
__device__ __forceinline__ void  stf(float* p, float v){ *p = v; }
__device__ __forceinline__ void  stf(bf16* p, float v){ *p = f2b(v); }

// async global->LDS, 16B per lane; LDS dest = wave-uniform base + lane*16
__device__ __forceinline__ void glds16(const bf16* g, unsigned short* l){
    __builtin_amdgcn_global_load_lds(
        (__attribute__((address_space(1))) void*)g,
        (__attribute__((address_space(3))) void*)l,
        16, 0, 0);
}

// ---------------- LayerNorm ----------------
__global__ __launch_bounds__(256)
void ln_kernel(const float* __restrict__ x, const float* __restrict__ g,
               const float* __restrict__ b, bf16* __restrict__ out, int nrows)
{
    int row  = blockIdx.x * 4 + (threadIdx.x >> 6);
    int lane = threadIdx.x & 63;
    if (row >= nrows) return;
    const float* xr = x + (size_t)row * DIM;
    float v[8];
    float s = 0.f, sq = 0.f;
    #pragma unroll
    for (int j = 0; j < 8; ++j) {
        float f = xr[lane + 64*j];
        v[j] = f; s += f; sq += f*f;
    }
    #pragma unroll
    for (int off = 32; off; off >>= 1) {
        s  += __shfl_xor(s,  off);
        sq += __shfl_xor(sq, off);
    }
    float mean = s * (1.f/DIM);
    float var  = sq * (1.f/DIM) - mean*mean;
    float rstd = rsqrtf(var + 1e-5f);
    bf16* orow = out + (size_t)row * DIM;
    #pragma unroll
    for (int j = 0; j < 8; ++j) {
        int c = lane + 64*j;
        orow[c] = f2b((v[j]-mean)*rstd*g[c] + b[c]);
    }
}

// ---------------- weight prep ----------------
__global__ __launch_bounds__(256)
void transpose_bf16_kernel(const float* __restrict__ W, bf16* __restrict__ Wt, int K, int N)
{
    __shared__ float tile[32][33];
    int n0 = blockIdx.x * 32, k0 = blockIdx.y * 32;
    int tx = threadIdx.x & 31, ty = threadIdx.x >> 5;
    #pragma unroll
    for (int p = 0; p < 4; ++p)
        tile[ty + p*8][tx] = W[(size_t)(k0 + ty + p*8)*N + n0 + tx];
    __syncthreads();
    #pragma unroll
    for (int p = 0; p < 4; ++p)
        Wt[(size_t)(n0 + ty + p*8)*K + k0 + tx] = f2b(tile[tx][ty + p*8]);
}

struct TPtrs { const float* src[8]; bf16* dst[8]; };
__global__ __launch_bounds__(256)
void transpose8_kernel(TPtrs p)
{
    __shared__ float tile[32][33];
    const float* W = p.src[blockIdx.z];
    bf16* Wt = p.dst[blockIdx.z];
    int n0 = blockIdx.x * 32, k0 = blockIdx.y * 32;
    int tx = threadIdx.x & 31, ty = threadIdx.x >> 5;
    #pragma unroll
    for (int q = 0; q < 4; ++q)
        tile[ty + q*8][tx] = W[(size_t)(k0 + ty + q*8)*512 + n0 + tx];
    __syncthreads();
    #pragma unroll
    for (int q = 0; q < 4; ++q)
        Wt[(size_t)(n0 + ty + q*8)*512 + k0 + tx] = f2b(tile[tx][ty + q*8]);
}

__global__ __launch_bounds__(256)
void cast_bf16_kernel(const float* __restrict__ in, bf16* __restrict__ out, int n)
{
    int i = blockIdx.x*256 + threadIdx.x;
    if (i < n) out[i] = f2b(in[i]);
}

// ---------------- V transpose ----------------
__global__ __launch_bounds__(256)
void v_transpose_kernel(const bf16* __restrict__ V, bf16* __restrict__ Vt, int T, int pitch)
{
    __shared__ __align__(16) unsigned short tile[64*64];
    const int tid = threadIdx.x;
    const int b = blockIdx.z, h = blockIdx.y;
    const int t0 = blockIdx.x * 64;
    #pragma unroll
    for (int it = 0; it < 2; ++it) {
        int e = tid + it*256;
        int t = e >> 3, c = e & 7;
        int gk = t0 + t;
        bf8_t v = {0,0,0,0,0,0,0,0};
        if (gk < T) v = *(const bf8_t*)(V + ((size_t)(b*T + gk))*DIM + h*HD + c*8);
        *(bf8_t*)&tile[t*64 + c*8] = v;
    }
    __syncthreads();
    #pragma unroll
    for (int it = 0; it < 2; ++it) {
        int e = tid + it*256;
        int d = e & 63, oc = e >> 6;
        unsigned short tmp[8];
        #pragma unroll
        for (int j = 0; j < 8; ++j) tmp[j] = tile[(oc*8 + j)*64 + d];
        *(bf8_t*)(Vt + ((size_t)((b*8 + h)*64 + d))*pitch + t0 + oc*8) = *(bf8_t*)tmp;
    }
}

struct OutPtrs { void* p[3]; };

// ---------------- MFMA GEMM 128x64 (for skinny N=512/1024 shapes; 3 blocks/CU) ----------------
template<int RESID, typename OUTT, bool GUARD>
__global__ __launch_bounds__(256)
void gemm_mfma_kernel(const bf16* __restrict__ A, const bf16* __restrict__ Wt,
                      const float* __restrict__ bias, const float* __restrict__ resid,
                      OutPtrs outs, int M, int K)
{
    __shared__ __align__(16) unsigned short As[2][128*64];
    __shared__ __align__(16) unsigned short Bs[2][64*64];
    const int tid  = threadIdx.x;
    const int wave = tid >> 6, lane = tid & 63;
    const int l16  = lane & 15, quad = lane >> 4;
    const int wm = (wave >> 1) * 64, wn = (wave & 1) * 32;
    const int m0 = blockIdx.y * 128, n0 = blockIdx.x * 64;
    OUTT* outp = (OUTT*)outs.p[n0 >> 9];
    const int lc0 = n0 & 511;
    const int lr = lane >> 3;            // row-in-8-row-chunk
    const int lc = (lane & 7) ^ lr;      // pre-swizzled col chunk

    f4_t acc[4][2];
    #pragma unroll
    for (int i = 0; i < 4; ++i) { acc[i][0] = f4_t{0,0,0,0}; acc[i][1] = f4_t{0,0,0,0}; }

    auto stage = [&](int k0, int bf) {
        #pragma unroll
        for (int i = 0; i < 4; ++i) {
            int r = (wave*4 + i)*8 + lr;          // 0..127
            int gr = m0 + r;
            if (GUARD) gr = (gr < M) ? gr : (M-1);
            glds16(A + (size_t)gr*K + k0 + lc*8, &As[bf][(wave*4 + i)*512]);
        }
        #pragma unroll
        for (int j = 0; j < 2; ++j) {
            int r = (wave*2 + j)*8 + lr;          // 0..63
            glds16(Wt + (size_t)(n0 + r)*K + k0 + lc*8, &Bs[bf][(wave*2 + j)*512]);
        }
    };

    stage(0, 0);
    __syncthreads();

    for (int k0 = 0; k0 < K; k0 += 64) {
        const int bf = (k0 >> 6) & 1;
        if (k0 + 64 < K) stage(k0 + 64, bf ^ 1);   // async, lands during compute
        #pragma unroll
        for (int kc = 0; kc < 2; ++kc) {
            const int cg = kc*4 + quad;
            bf8_t af[4], bfr[2];
            #pragma unroll
            for (int mt = 0; mt < 4; ++mt) {
                int r = wm + mt*16 + l16;
                af[mt] = *(const bf8_t*)&As[bf][r*64 + ((cg ^ (r&7))*8)];
            }
            #pragma unroll
            for (int nt = 0; nt < 2; ++nt) {
                int r = wn + nt*16 + l16;
                bfr[nt] = *(const bf8_t*)&Bs[bf][r*64 + ((cg ^ (r&7))*8)];
            }
            #pragma unroll
            for (int mt = 0; mt < 4; ++mt)
                #pragma unroll
                for (int nt = 0; nt < 2; ++nt)
                    acc[mt][nt] = __builtin_amdgcn_mfma_f32_16x16x32_bf16(af[mt], bfr[nt], acc[mt][nt], 0, 0, 0);
        }
        __syncthreads();
    }

    #pragma unroll
    for (int mt = 0; mt < 4; ++mt) {
        #pragma unroll
        for (int r_ = 0; r_ < 4; ++r_) {
            int row = m0 + wm + mt*16 + quad*4 + r_;
            if (GUARD && row >= M) continue;
            size_t rb = (size_t)row * 512;
            #pragma unroll
            for (int nt = 0; nt < 2; ++nt) {
                int col = lc0 + wn + nt*16 + l16;
                float v = acc[mt][nt][r_];
                if (bias) v += bias[col];
                if (RESID) v += resid[rb + col];
                stf(&outp[rb + col], v);
            }
        }
    }
}

// ---------------- MFMA GEMM 128x128 (m97 shape: 2x intensity; for N>=1024 / big-K) ----------------
// 4 waves, each 64x64 output (4x4 f4_t acc). glds16 double-buffer, 64KB LDS
// (2 blocks/CU), 1 barrier per k-step. Pre-swizzled global source keeps LDS
// linear for the HW while the read side uses the XOR swizzle.
template<int RESID, typename OUTT, bool GUARD>
__global__ __launch_bounds__(256)
void gemm128_kernel(const bf16* __restrict__ A, const bf16* __restrict__ Wt,
                    const float* __restrict__ bias, const float* __restrict__ resid,
                    OutPtrs outs, int M, int K)
{
    __shared__ __align__(16) unsigned short As[2][128*64];
    __shared__ __align__(16) unsigned short Bs[2][128*64];
    const int tid  = threadIdx.x;
    const int wave = tid >> 6, lane = tid & 63;
    const int l16  = lane & 15, quad = lane >> 4;
    const int wm = (wave >> 1) * 64, wn = (wave & 1) * 64;
    const int m0 = blockIdx.y * 128, n0 = blockIdx.x * 128;
    OUTT* outp = (OUTT*)outs.p[n0 >> 9];
    const int lc0 = n0 & 511;
    const int lr = lane >> 3;
    const int lc = (lane & 7) ^ lr;

    f4_t acc[4][4];
    #pragma unroll
    for (int i = 0; i < 4; ++i)
        #pragma unroll
        for (int j = 0; j < 4; ++j) acc[i][j] = f4_t{0,0,0,0};

    auto stage = [&](int k0, int bf) {
        #pragma unroll
        for (int i = 0; i < 4; ++i) {
            int r = (wave*4 + i)*8 + lr;          // 0..127
            int gr = m0 + r;
            if (GUARD) gr = (gr < M) ? gr : (M-1);
            glds16(A + (size_t)gr*K + k0 + lc*8, &As[bf][(wave*4 + i)*512]);
        }
        #pragma unroll
        for (int i = 0; i < 4; ++i) {
            int r = (wave*4 + i)*8 + lr;          // 0..127
            glds16(Wt + (size_t)(n0 + r)*K + k0 + lc*8, &Bs[bf][(wave*4 + i)*512]);
        }
    };

    stage(0, 0);
    __syncthreads();

    for (int k0 = 0; k0 < K; k0 += 64) {
        const int bf = (k0 >> 6) & 1;
        if (k0 + 64 < K) stage(k0 + 64, bf ^ 1);   // async, lands during compute
        #pragma unroll
        for (int kc = 0; kc < 2; ++kc) {
            const int cg = kc*4 + quad;
            bf8_t af[4], bfr[4];
            #pragma unroll
            for (int mt = 0; mt < 4; ++mt) {
                int r = wm + mt*16 + l16;
                af[mt] = *(const bf8_t*)&As[bf][r*64 + ((cg ^ (r&7))*8)];
            }
            #pragma unroll
            for (int nt = 0; nt < 4; ++nt) {
                int r = wn + nt*16 + l16;
                bfr[nt] = *(const bf8_t*)&Bs[bf][r*64 + ((cg ^ (r&7))*8)];
            }
            #pragma unroll
            for (int mt = 0; mt < 4; ++mt)
                #pragma unroll
                for (int nt = 0; nt < 4; ++nt)
                    acc[mt][nt] = __builtin_amdgcn_mfma_f32_16x16x32_bf16(af[mt], bfr[nt], acc[mt][nt], 0, 0, 0);
        }
        __syncthreads();
    }

    #pragma unroll
    for (int mt = 0; mt < 4; ++mt) {
        #pragma unroll
        for (int r_ = 0; r_ < 4; ++r_) {
            int row = m0 + wm + mt*16 + quad*4 + r_;
            if (GUARD && row >= M) continue;
            size_t rb = (size_t)row * 512;
            #pragma unroll
            for (int nt = 0; nt < 4; ++nt) {
                int col = lc0 + wn + nt*16 + l16;
                float v = acc[mt][nt][r_];
                if (bias) v += bias[col];
                if (RESID) v += resid[rb + col];
                stf(&outp[rb + col], v);
            }
        }
    }
}

// ---------------- MFMA GEGLU: global_load_lds single-buffer ----------------
__global__ __launch_bounds__(256)
void geglu_mfma_kernel(const bf16* __restrict__ A, const bf16* __restrict__ WtG,
                       const float* __restrict__ bias, bf16* __restrict__ outp)
{
    __shared__ __align__(16) unsigned short As[128*64];
    __shared__ __align__(16) unsigned short Bys[64*64];
    __shared__ __align__(16) unsigned short Bgs[64*64];
    const int tid  = threadIdx.x;
    const int wave = tid >> 6, lane = tid & 63;
    const int l16  = lane & 15, quad = lane >> 4;
    const int m0 = blockIdx.y * 128, n0 = blockIdx.x * 64;
    const int lr = lane >> 3;
    const int lc = (lane & 7) ^ lr;

    f4_t accy[2][4], accg[2][4];
    #pragma unroll
    for (int i = 0; i < 2; ++i)
        #pragma unroll
        for (int j = 0; j < 4; ++j) { accy[i][j] = f4_t{0,0,0,0}; accg[i][j] = f4_t{0,0,0,0}; }

    for (int k0 = 0; k0 < DIM; k0 += 64) {
        #pragma unroll
        for (int i = 0; i < 4; ++i) {
            int r = (wave*4 + i)*8 + lr;
            glds16(A + (size_t)(m0 + r)*DIM + k0 + lc*8, &As[(wave*4 + i)*512]);
        }
        #pragma unroll
        for (int j = 0; j < 2; ++j) {
            int r = (wave*2 + j)*8 + lr;
            glds16(WtG + (size_t)(n0 + r)*DIM + k0 + lc*8, &Bys[(wave*2 + j)*512]);
            glds16(WtG + (size_t)(2048 + n0 + r)*DIM + k0 + lc*8, &Bgs[(wave*2 + j)*512]);
        }
        __syncthreads();   // drains glds
        #pragma unroll
        for (int kc = 0; kc < 2; ++kc) {
            const int cg = kc*4 + quad;
            bf8_t af[2];
            #pragma unroll
            for (int mt = 0; mt < 2; ++mt) {
                int r = wave*32 + mt*16 + l16;
                af[mt] = *(const bf8_t*)&As[r*64 + ((cg ^ (r&7))*8)];
            }
            #pragma unroll
            for (int nt = 0; nt < 4; ++nt) {
                int r = nt*16 + l16;
                bf8_t by = *(const bf8_t*)&Bys[r*64 + ((cg ^ (r&7))*8)];
                bf8_t bg = *(const bf8_t*)&Bgs[r*64 + ((cg ^ (r&7))*8)];
                #pragma unroll
                for (int mt = 0; mt < 2; ++mt) {
                    accy[mt][nt] = __builtin_amdgcn_mfma_f32_16x16x32_bf16(af[mt], by, accy[mt][nt], 0, 0, 0);
                    accg[mt][nt] = __builtin_amdgcn_mfma_f32_16x16x32_bf16(af[mt], bg, accg[mt][nt], 0, 0, 0);
                }
            }
        }
        __syncthreads();
    }

    #pragma unroll
    for (int mt = 0; mt < 2; ++mt) {
        #pragma unroll
        for (int r_ = 0; r_ < 4; ++r_) {
            int row = m0 + wave*32 + mt*16 + quad*4 + r_;
            size_t rb = (size_t)row * 2048;
            #pragma unroll
            for (int nt = 0; nt < 4; ++nt) {
                int col = n0 + nt*16 + l16;
                float y = accy[mt][nt][r_] + bias[col];
                float g = accg[mt][nt][r_] + bias[2048 + col];
                float t = tanhf(0.7978845608f*g*(1.f + 0.044715f*g*g));
                outp[rb + col] = f2b(y * 0.5f * g * (1.f + t));
            }
        }
    }
}

// ---------------- MFMA flash attention (R10 structure, unsplit) ----------------
// reg-staged K/V double-issue, Ps-LDS P redistribution, 2 barriers/tile.
// R14 evidence: split-T doubled blocks but occupancy/duration unchanged
// (residency capped ~2 blocks/CU by total reg allocation) -> unsplit is
// strictly better (no combine pass, no f32 partial traffic).
__global__ __launch_bounds__(512)
void attn_mfma_kernel(const bf16* __restrict__ Qm, const bf16* __restrict__ Km,
                      const bf16* __restrict__ VtG, bf16* __restrict__ Om,
                      int T, int vpitch)
{
    __shared__ __align__(16) unsigned short Ks[64*64];
    __shared__ __align__(16) unsigned short Vts[64*64];
    __shared__ __align__(16) unsigned short Ps[8][16*64];

    const int tid  = threadIdx.x;
    const int wave = tid >> 6, lane = tid & 63;
    const int l16  = lane & 15, quad = lane >> 4;
    const int b = blockIdx.z, h = blockIdx.y;
    const int qblk = blockIdx.x * 128;
    const int sr = tid >> 3, sc_ = tid & 7;   // staging: row 0..63, chunk 0..7

    bf8_t ones;
    #pragma unroll
    for (int j = 0; j < 8; ++j) ((unsigned short*)&ones)[j] = 0x3F80;

    // Q fragments (B-operand layout), pre-scaled by D^-0.5 * log2(e)
    bf8_t qf[2];
    {
        const bf16* qp = Qm + ((size_t)(b*SEQ + qblk + wave*16 + l16))*DIM + h*HD + quad*8;
        #pragma unroll
        for (int kc = 0; kc < 2; ++kc) {
            bf8_t v = *(const bf8_t*)(qp + kc*32);
            unsigned short* u = (unsigned short*)&v;
            unsigned int* w = (unsigned int*)&v;
            #pragma unroll
            for (int j = 0; j < 4; ++j) {
                float f0 = b2f(*(bf16*)&u[2*j])   * 0.1803368801f;
                float f1 = b2f(*(bf16*)&u[2*j+1]) * 0.1803368801f;
                w[j] = packbf2(f0, f1);
            }
            qf[kc] = v;
        }
    }

    f4_t o[4];
    #pragma unroll
    for (int dt = 0; dt < 4; ++dt) o[dt] = f4_t{0,0,0,0};
    f4_t lacc = {0,0,0,0};

    const bf16* Kbase = Km + (size_t)b*T*DIM + h*HD;
    const bf16* Vbase = VtG + ((size_t)((b*8 + h)*64 + sr))*vpitch;

    // prologue: load tile 0 into registers
    bf8_t kq, vq;
    kq = bf8_t{0,0,0,0,0,0,0,0};
    if (sr < T) kq = *(const bf8_t*)(Kbase + (size_t)sr*DIM + sc_*8);
    vq = *(const bf8_t*)(Vbase + sc_*8);

    const int ntiles = (T + 63) >> 6;
    for (int t0 = 0; t0 < ntiles; ++t0) {
        const int kb = t0 << 6;
        // ---- regs -> LDS (swizzled b128) ----
        *(bf8_t*)&Ks[sr*64 + ((sc_ ^ (sr&7))*8)]  = kq;
        *(bf8_t*)&Vts[sr*64 + ((sc_ ^ (sr&7))*8)] = vq;
        __syncthreads();
        // ---- prefetch next tile (overlaps compute) ----
        if (t0 + 1 < ntiles) {
            int gk = kb + 64 + sr;
            kq = bf8_t{0,0,0,0,0,0,0,0};
            if (gk < T) kq = *(const bf8_t*)(Kbase + (size_t)gk*DIM + sc_*8);
            vq = *(const bf8_t*)(Vbase + kb + 64 + sc_*8);
        }

        bf8_t kf[4][2], vf[4][2];
        #pragma unroll
        for (int t = 0; t < 4; ++t) {
            int r = t*16 + l16;
            #pragma unroll
            for (int kc = 0; kc < 2; ++kc) {
                int cg = kc*4 + quad;
                kf[t][kc] = *(const bf8_t*)&Ks[r*64 + ((cg ^ (r&7))*8)];
                vf[t][kc] = *(const bf8_t*)&Vts[r*64 + ((cg ^ (r&7))*8)];
            }
        }
        const bool tail = (kb + 64 > T);

        f4_t sc4[4];
        #pragma unroll
        for (int km = 0; km < 4; ++km) {
            f4_t c = {0,0,0,0};
            c = __builtin_amdgcn_mfma_f32_16x16x32_bf16(kf[km][0], qf[0], c, 0, 0, 0);
            c = __builtin_amdgcn_mfma_f32_16x16x32_bf16(kf[km][1], qf[1], c, 0, 0, 0);
            sc4[km] = c;
        }
        if (tail) {
            #pragma unroll
            for (int km = 0; km < 4; ++km)
                #pragma unroll
                for (int r = 0; r < 4; ++r)
                    if (kb + km*16 + quad*4 + r >= T) sc4[km][r] = -1e30f;
        }
        #pragma unroll
        for (int km = 0; km < 4; ++km) {
            uint2 w;
            w.x = packbf2(exp2f(sc4[km][0]), exp2f(sc4[km][1]));
            w.y = packbf2(exp2f(sc4[km][2]), exp2f(sc4[km][3]));
            int chunk = 2*km + (quad >> 1);
            int a = l16*64 + ((chunk ^ (l16 & 7))*8) + (quad & 1)*4;
            *(uint2*)&Ps[wave][a] = w;
        }
        #pragma unroll
        for (int kc = 0; kc < 2; ++kc) {
            int cg = kc*4 + quad;
            bf8_t pf = *(const bf8_t*)&Ps[wave][l16*64 + ((cg ^ (l16 & 7))*8)];
            lacc = __builtin_amdgcn_mfma_f32_16x16x32_bf16(ones, pf, lacc, 0, 0, 0);
            #pragma unroll
            for (int dt = 0; dt < 4; ++dt)
                o[dt] = __builtin_amdgcn_mfma_f32_16x16x32_bf16(vf[dt][kc], pf, o[dt], 0, 0, 0);
        }
        __syncthreads();
    }

    {
        float inv = 1.f / lacc[0];
        int tok = qblk + wave*16 + l16;
        size_t base = ((size_t)(b*SEQ + tok))*DIM + h*HD;
        #pragma unroll
        for (int dt = 0; dt < 4; ++dt) {
            uint2 w;
            w.x = packbf2(o[dt][0]*inv, o[dt][1]*inv);
            w.y = packbf2(o[dt][2]*inv, o[dt][3]*inv);
            *(uint2*)(Om + base + dt*16 + quad*4) = w;
        }
    }
}

extern "C" void kernel_launch(void* const* d_in, const int* in_sizes, int n_in,
                              void* d_out, int out_size, void* d_ws, size_t ws_size,
                              hipStream_t stream)
{
    (void)in_sizes; (void)n_in; (void)out_size; (void)ws_size;
    const float* x    = (const float*)d_in[0];
    const float* ctx  = (const float*)d_in[1];
    const float* ln1g = (const float*)d_in[2];
    const float* ln1b = (const float*)d_in[3];
    const float* wq1  = (const float*)d_in[4];
    const float* wk1  = (const float*)d_in[5];
    const float* wv1  = (const float*)d_in[6];
    const float* wo1  = (const float*)d_in[7];
    const float* bo1  = (const float*)d_in[8];
    const float* ln2g = (const float*)d_in[9];
    const float* ln2b = (const float*)d_in[10];
    const float* wq2  = (const float*)d_in[11];
    const float* wk2  = (const float*)d_in[12];
    const float* wv2  = (const float*)d_in[13];
    const float* wo2  = (const float*)d_in[14];
    const float* bo2  = (const float*)d_in[15];
    const float* ln3g = (const float*)d_in[16];
    const float* ln3b = (const float*)d_in[17];
    const float* gw   = (const float*)d_in[18];
    const float* gb   = (const float*)d_in[19];
    const float* ow   = (const float*)d_in[20];
    const float* ob   = (const float*)d_in[21];
    float* out = (float*)d_out;

    char* ws = (char*)d_ws;
    bf16* An  = (bf16*)(ws);
    bf16* VtG = (bf16*)(ws);                     // alias An
    bf16* Qb  = (bf16*)(ws + ((size_t)8<<20));
    bf16* Kb  = (bf16*)(ws + ((size_t)16<<20));
    bf16* Vb  = (bf16*)(ws + ((size_t)24<<20));
    bf16* Ob  = (bf16*)(ws + ((size_t)32<<20));
    bf16* FF  = Qb;
    float* Hf = out;
    bf16* WT  = (bf16*)(ws + ((size_t)40<<20));
    bf16* wq1T = WT + 0*262144, *wk1T = WT + 1*262144, *wv1T = WT + 2*262144, *wo1T = WT + 3*262144;
    bf16* wq2T = WT + 4*262144, *wk2T = WT + 5*262144, *wv2T = WT + 6*262144, *wo2T = WT + 7*262144;
    bf16* gwT  = (bf16*)(ws + ((size_t)44<<20));
    bf16* owT  = (bf16*)(ws + ((size_t)48<<20));
    bf16* ctxb = (bf16*)(ws + ((size_t)50<<20));
    bf16* VtG2 = (bf16*)(ws + ((size_t)50<<20) + ((size_t)512<<10));

    dim3 blk(256);
    dim3 blkA(512);

    // ---- weight prep ----
    TPtrs tp;
    tp.src[0]=wq1; tp.src[1]=wk1; tp.src[2]=wv1; tp.src[3]=wo1;
    tp.src[4]=wq2; tp.src[5]=wk2; tp.src[6]=wv2; tp.src[7]=wo2;
    tp.dst[0]=wq1T; tp.dst[1]=wk1T; tp.dst[2]=wv1T; tp.dst[3]=wo1T;
    tp.dst[4]=wq2T; tp.dst[5]=wk2T; tp.dst[6]=wv2T; tp.dst[7]=wo2T;
    transpose8_kernel<<<dim3(16,16,8), blk, 0, stream>>>(tp);
    transpose_bf16_kernel<<<dim3(128,16), blk, 0, stream>>>(gw, gwT, DIM, 4096);
    transpose_bf16_kernel<<<dim3(16,64), blk, 0, stream>>>(ow, owT, 2048, DIM);
    cast_bf16_kernel<<<dim3((NCTX*DIM+255)/256), blk, 0, stream>>>(ctx, ctxb, NCTX*DIM);

    dim3 gLN(NTOK/4);
    dim3 gQKV(12, 64);        // 128x128 tiles, N=1536 -> Qb,Kb,Vb
    dim3 gG(8, 64);           // 128x64, N=512
    dim3 gKVx(16, 2);         // 128x64, N=1024, M=154 (guarded) -> Kb,Vb
    dim3 gGEGLU(32, 64);
    dim3 gOUT(4, 64);         // 128x128 tiles, N=512, K=2048
    dim3 gATT(SEQ/128, NHEAD, BATCH);
    OutPtrs oQKV{{Qb, Kb, Vb}};
    OutPtrs oKVx{{Kb, Vb, nullptr}};
    OutPtrs oQ{{Qb, nullptr, nullptr}};
    OutPtrs oH{{Hf, nullptr, nullptr}};
    OutPtrs oOut{{out, nullptr, nullptr}};

    // ---- self-attention ----
    ln_kernel<<<gLN, blk, 0, stream>>>(x, ln1g, ln1b, An, NTOK);
    gemm128_kernel<0,bf16,false><<<gQKV, blk, 0, stream>>>(An, wq1T, nullptr, nullptr, oQKV, NTOK, DIM);
    v_transpose_kernel<<<dim3(SEQ/64, NHEAD, BATCH), blk, 0, stream>>>(Vb, VtG, SEQ, SEQ);
    attn_mfma_kernel<<<gATT, blkA, 0, stream>>>(Qb, Kb, VtG, Ob, SEQ, SEQ);
    gemm_mfma_kernel<1,float,false><<<gG, blk, 0, stream>>>(Ob, wo1T, bo1, x, oH, NTOK, DIM);

    // ---- cross-attention ----
    ln_kernel<<<gLN, blk, 0, stream>>>(Hf, ln2g, ln2b, An, NTOK);
    gemm_mfma_kernel<0,bf16,false><<<gG, blk, 0, stream>>>(An, wq2T, nullptr, nullptr, oQ, NTOK, DIM);
    gemm_mfma_kernel<0,bf16,true><<<gKVx, blk, 0, stream>>>(ctxb, wk2T, nullptr, nullptr, oKVx, NCTX, DIM);
    v_transpose_kernel<<<dim3(2, NHEAD, BATCH), blk, 0, stream>>>(Vb, VtG2, CTXLEN, 128);
    attn_mfma_kernel<<<gATT, blkA, 0, stream>>>(Qb, Kb, VtG2, Ob, CTXLEN, 128);
    gemm_mfma_kernel<1,float,false><<<gG, blk, 0, stream>>>(Ob, wo2T, bo2, Hf, oH, NTOK, DIM);

    // ---- GEGLU FFN + output projection ----
    ln_kernel<<<gLN, blk, 0, stream>>>(Hf, ln3g, ln3b, An, NTOK);
    geglu_mfma_kernel<<<gGEGLU, blk, 0, stream>>>(An, gwT, gb, FF);
    gemm128_kernel<1,float,false><<<gOUT, blk, 0, stream>>>(FF, owT, ob, Hf, oOut, NTOK, 2048);
}

// Round 7
// 453.115 us; speedup vs baseline: 1.0595x; 1.0595x over previous
//
#include <hip/hip_runtime.h>
#include <hip/hip_bf16.h>
#include <math.h>

#define DIM 512
#define NHEAD 8
#define HD 64
#define BATCH 2
#define SEQ 4096
#define CTXLEN 77
#define NTOK (BATCH*SEQ)     // 8192
#define NCTX (BATCH*CTXLEN)  // 154

typedef __hip_bfloat16 bf16;
typedef __attribute__((ext_vector_type(8))) short bf8_t;   // 8 bf16 (4 VGPRs)
typedef __attribute__((ext_vector_type(4))) float f4_t;    // 4 fp32 acc

__device__ __forceinline__ float b2f(bf16 v){ return __bfloat162float(v); }
__device__ __forceinline__ bf16  f2b(float v){ return __float2bfloat16(v); }
// fast bf16 pair pack: round-half-up + one v_perm_b32; low element = a, high = b
__device__ __forceinline__ unsigned int packbf2(float a, float b){
    unsigned int au = __float_as_uint(a) + 0x8000u;
    unsigned int bu = __float_as_uint(b) + 0x8000u;
    return __builtin_amdgcn_perm(bu, au, 0x07060302u);
}
__device__ __forceinline__ void  stf(float* p, float v){ *p = v; }
__device__ __forceinline__ void  stf(bf16* p, float v){ *p = f2b(v); }

// ---------------- LayerNorm ----------------
__global__ __launch_bounds__(256)
void ln_kernel(const float* __restrict__ x, const float* __restrict__ g,
               const float* __restrict__ b, bf16* __restrict__ out, int nrows)
{
    int row  = blockIdx.x * 4 + (threadIdx.x >> 6);
    int lane = threadIdx.x & 63;
    if (row >= nrows) return;
    const float* xr = x + (size_t)row * DIM;
    float v[8];
    float s = 0.f, sq = 0.f;
    #pragma unroll
    for (int j = 0; j < 8; ++j) {
        float f = xr[lane + 64*j];
        v[j] = f; s += f; sq += f*f;
    }
    #pragma unroll
    for (int off = 32; off; off >>= 1) {
        s  += __shfl_xor(s,  off);
        sq += __shfl_xor(sq, off);
    }
    float mean = s * (1.f/DIM);
    float var  = sq * (1.f/DIM) - mean*mean;
    float rstd = rsqrtf(var + 1e-5f);
    bf16* orow = out + (size_t)row * DIM;
    #pragma unroll
    for (int j = 0; j < 8; ++j) {
        int c = lane + 64*j;
        orow[c] = f2b((v[j]-mean)*rstd*g[c] + b[c]);
    }
}

// ---------------- fused weight prep: 8x 512x512 transposes + gw + ow + ctx cast ----------------
// One launch replaces 4. Flat block ranges:
//   [0,2048)    : 8 attention weight transposes (512x512, 16x16 tiles each)
//   [2048,4096) : gw transpose  (K=512 -> N=4096, 128x16 tiles)
//   [4096,5120) : ow transpose  (K=2048 -> N=512, 16x64 tiles)
//   [5120,5428) : ctx f32->bf16 cast (308*256 == 78848 == NCTX*DIM exactly)
struct PrepArgs {
    const float* src8[8]; bf16* dst8[8];
    const float* gw; bf16* gwT;
    const float* ow; bf16* owT;
    const float* ctx; bf16* ctxb;
};
__global__ __launch_bounds__(256)
void prep_kernel(PrepArgs a)
{
    __shared__ float tile[32][33];
    const int bid = blockIdx.x;
    const int tx = threadIdx.x & 31, ty = threadIdx.x >> 5;
    const float* W; bf16* Wt; int K, N, n0, k0;
    if (bid < 2048) {
        int z = bid >> 8, t = bid & 255;
        W = a.src8[z]; Wt = a.dst8[z]; K = 512; N = 512;
        n0 = (t & 15)*32; k0 = (t >> 4)*32;
    } else if (bid < 4096) {
        int t = bid - 2048;
        W = a.gw; Wt = a.gwT; K = 512; N = 4096;
        n0 = (t & 127)*32; k0 = (t >> 7)*32;
    } else if (bid < 5120) {
        int t = bid - 4096;
        W = a.ow; Wt = a.owT; K = 2048; N = 512;
        n0 = (t & 15)*32; k0 = (t >> 4)*32;
    } else {
        int i = (bid - 5120)*256 + threadIdx.x;
        a.ctxb[i] = f2b(a.ctx[i]);
        return;
    }
    #pragma unroll
    for (int p = 0; p < 4; ++p)
        tile[ty + p*8][tx] = W[(size_t)(k0 + ty + p*8)*N + n0 + tx];
    __syncthreads();
    #pragma unroll
    for (int p = 0; p < 4; ++p)
        Wt[(size_t)(n0 + ty + p*8)*K + k0 + tx] = f2b(tile[tx][ty + p*8]);
}

// ---------------- V transpose (cross-attn only; tiny) ----------------
__global__ __launch_bounds__(256)
void v_transpose_kernel(const bf16* __restrict__ V, bf16* __restrict__ Vt, int T, int pitch)
{
    __shared__ __align__(16) unsigned short tile[64*64];
    const int tid = threadIdx.x;
    const int b = blockIdx.z, h = blockIdx.y;
    const int t0 = blockIdx.x * 64;
    #pragma unroll
    for (int it = 0; it < 2; ++it) {
        int e = tid + it*256;
        int t = e >> 3, c = e & 7;
        int gk = t0 + t;
        bf8_t v = {0,0,0,0,0,0,0,0};
        if (gk < T) v = *(const bf8_t*)(V + ((size_t)(b*T + gk))*DIM + h*HD + c*8);
        *(bf8_t*)&tile[t*64 + c*8] = v;
    }
    __syncthreads();
    #pragma unroll
    for (int it = 0; it < 2; ++it) {
        int e = tid + it*256;
        int d = e & 63, oc = e >> 6;
        unsigned short tmp[8];
        #pragma unroll
        for (int j = 0; j < 8; ++j) tmp[j] = tile[(oc*8 + j)*64 + d];
        *(bf8_t*)(Vt + ((size_t)((b*8 + h)*64 + d))*pitch + t0 + oc*8) = *(bf8_t*)tmp;
    }
}

// ---------------- MFMA GEMM with register-prefetch double-buffer (R10 form) ----------------
// VT: blocks whose output lands in p[2] (V of QKV) write the accumulator
// directly in the attention's transposed V layout [ (b*8+h)*64+d ][ tok ]
// (lane holds 4 consecutive tokens for fixed d -> packed 8B stores), which
// deletes the separate v_transpose kernel and the Vb roundtrip.
struct OutPtrs { void* p[3]; };
template<int RESID, typename OUTT, bool GUARD, bool VT>
__global__ __launch_bounds__(256)
void gemm_mfma_kernel(const bf16* __restrict__ A, const bf16* __restrict__ Wt,
                      const float* __restrict__ bias, const float* __restrict__ resid,
                      OutPtrs outs, int M, int K)
{
    __shared__ __align__(16) unsigned short As[128*64];
    __shared__ __align__(16) unsigned short Bs[64*64];
    const int tid  = threadIdx.x;
    const int wave = tid >> 6, lane = tid & 63;
    const int l16  = lane & 15, quad = lane >> 4;
    const int wm = (wave >> 1) * 64, wn = (wave & 1) * 32;
    const int m0 = blockIdx.y * 128, n0 = blockIdx.x * 64;
    OUTT* outp = (OUTT*)outs.p[n0 >> 9];
    const int lc0 = n0 & 511;
    const int sr = tid >> 3, sc_ = tid & 7;   // staging row/chunk

    f4_t acc[4][2];
    #pragma unroll
    for (int i = 0; i < 4; ++i) { acc[i][0] = f4_t{0,0,0,0}; acc[i][1] = f4_t{0,0,0,0}; }

    // prologue: prefetch k0=0 tiles into registers
    bf8_t pa[4], pb[2];
    #pragma unroll
    for (int p = 0; p < 4; ++p) {
        int r = sr + p*32;
        int gr = m0 + r;
        if (GUARD) gr = (gr < M) ? gr : (M-1);
        pa[p] = *(const bf8_t*)(A + (size_t)gr*K + sc_*8);
    }
    #pragma unroll
    for (int p = 0; p < 2; ++p)
        pb[p] = *(const bf8_t*)(Wt + (size_t)(n0 + sr + p*32)*K + sc_*8);

    for (int k0 = 0; k0 < K; k0 += 64) {
        // regs -> LDS
        #pragma unroll
        for (int p = 0; p < 4; ++p) {
            int r = sr + p*32;
            *(bf8_t*)&As[r*64 + ((sc_ ^ (r&7))*8)] = pa[p];
        }
        #pragma unroll
        for (int p = 0; p < 2; ++p) {
            int r = sr + p*32;
            *(bf8_t*)&Bs[r*64 + ((sc_ ^ (r&7))*8)] = pb[p];
        }
        __syncthreads();
        // prefetch next k-tile (overlaps with compute below)
        if (k0 + 64 < K) {
            #pragma unroll
            for (int p = 0; p < 4; ++p) {
                int r = sr + p*32;
                int gr = m0 + r;
                if (GUARD) gr = (gr < M) ? gr : (M-1);
                pa[p] = *(const bf8_t*)(A + (size_t)gr*K + k0 + 64 + sc_*8);
            }
            #pragma unroll
            for (int p = 0; p < 2; ++p)
                pb[p] = *(const bf8_t*)(Wt + (size_t)(n0 + sr + p*32)*K + k0 + 64 + sc_*8);
        }
        #pragma unroll
        for (int kc = 0; kc < 2; ++kc) {
            const int cg = kc*4 + quad;
            bf8_t af[4], bfr[2];
            #pragma unroll
            for (int mt = 0; mt < 4; ++mt) {
                int r = wm + mt*16 + l16;
                af[mt] = *(const bf8_t*)&As[r*64 + ((cg ^ (r&7))*8)];
            }
            #pragma unroll
            for (int nt = 0; nt < 2; ++nt) {
                int r = wn + nt*16 + l16;
                bfr[nt] = *(const bf8_t*)&Bs[r*64 + ((cg ^ (r&7))*8)];
            }
            #pragma unroll
            for (int mt = 0; mt < 4; ++mt)
                #pragma unroll
                for (int nt = 0; nt < 2; ++nt)
                    acc[mt][nt] = __builtin_amdgcn_mfma_f32_16x16x32_bf16(af[mt], bfr[nt], acc[mt][nt], 0, 0, 0);
        }
        __syncthreads();
    }

    if (VT && (n0 >> 9) == 2) {
        // transposed V write: VtG[((b*8+h)*64 + d)*SEQ + tok], 4 tokens per store
        bf16* vt = (bf16*)outs.p[2];
        #pragma unroll
        for (int mt = 0; mt < 4; ++mt) {
            int row = m0 + wm + mt*16 + quad*4;
            int bb = row >> 12, tok = row & 4095;
            #pragma unroll
            for (int nt = 0; nt < 2; ++nt) {
                int c = lc0 + wn + nt*16 + l16;
                int h = c >> 6, d = c & 63;
                uint2 w;
                w.x = packbf2(acc[mt][nt][0], acc[mt][nt][1]);
                w.y = packbf2(acc[mt][nt][2], acc[mt][nt][3]);
                *(uint2*)(vt + ((size_t)((bb*8 + h)*64 + d))*SEQ + tok) = w;
            }
        }
        return;
    }

    #pragma unroll
    for (int mt = 0; mt < 4; ++mt) {
        #pragma unroll
        for (int r_ = 0; r_ < 4; ++r_) {
            int row = m0 + wm + mt*16 + quad*4 + r_;
            if (GUARD && row >= M) continue;
            size_t rb = (size_t)row * 512;
            #pragma unroll
            for (int nt = 0; nt < 2; ++nt) {
                int col = lc0 + wn + nt*16 + l16;
                float v = acc[mt][nt][r_];
                if (bias) v += bias[col];
                if (RESID) v += resid[rb + col];
                stf(&outp[rb + col], v);
            }
        }
    }
}

// ---------------- MFMA GEGLU with register-prefetch double-buffer (R10 form) ----------------
__global__ __launch_bounds__(256)
void geglu_mfma_kernel(const bf16* __restrict__ A, const bf16* __restrict__ WtG,
                       const float* __restrict__ bias, bf16* __restrict__ outp)
{
    __shared__ __align__(16) unsigned short As[128*64];
    __shared__ __align__(16) unsigned short Bys[64*64];
    __shared__ __align__(16) unsigned short Bgs[64*64];
    const int tid  = threadIdx.x;
    const int wave = tid >> 6, lane = tid & 63;
    const int l16  = lane & 15, quad = lane >> 4;
    const int m0 = blockIdx.y * 128, n0 = blockIdx.x * 64;
    const int sr = tid >> 3, sc_ = tid & 7;

    f4_t accy[2][4], accg[2][4];
    #pragma unroll
    for (int i = 0; i < 2; ++i)
        #pragma unroll
        for (int j = 0; j < 4; ++j) { accy[i][j] = f4_t{0,0,0,0}; accg[i][j] = f4_t{0,0,0,0}; }

    bf8_t pa[4], py[2], pg[2];
    #pragma unroll
    for (int p = 0; p < 4; ++p)
        pa[p] = *(const bf8_t*)(A + (size_t)(m0 + sr + p*32)*DIM + sc_*8);
    #pragma unroll
    for (int p = 0; p < 2; ++p) {
        py[p] = *(const bf8_t*)(WtG + (size_t)(n0 + sr + p*32)*DIM + sc_*8);
        pg[p] = *(const bf8_t*)(WtG + (size_t)(2048 + n0 + sr + p*32)*DIM + sc_*8);
    }

    for (int k0 = 0; k0 < DIM; k0 += 64) {
        #pragma unroll
        for (int p = 0; p < 4; ++p) {
            int r = sr + p*32;
            *(bf8_t*)&As[r*64 + ((sc_ ^ (r&7))*8)] = pa[p];
        }
        #pragma unroll
        for (int p = 0; p < 2; ++p) {
            int r = sr + p*32;
            *(bf8_t*)&Bys[r*64 + ((sc_ ^ (r&7))*8)] = py[p];
            *(bf8_t*)&Bgs[r*64 + ((sc_ ^ (r&7))*8)] = pg[p];
        }
        __syncthreads();
        if (k0 + 64 < DIM) {
            #pragma unroll
            for (int p = 0; p < 4; ++p)
                pa[p] = *(const bf8_t*)(A + (size_t)(m0 + sr + p*32)*DIM + k0 + 64 + sc_*8);
            #pragma unroll
            for (int p = 0; p < 2; ++p) {
                py[p] = *(const bf8_t*)(WtG + (size_t)(n0 + sr + p*32)*DIM + k0 + 64 + sc_*8);
                pg[p] = *(const bf8_t*)(WtG + (size_t)(2048 + n0 + sr + p*32)*DIM + k0 + 64 + sc_*8);
            }
        }
        #pragma unroll
        for (int kc = 0; kc < 2; ++kc) {
            const int cg = kc*4 + quad;
            bf8_t af[2];
            #pragma unroll
            for (int mt = 0; mt < 2; ++mt) {
                int r = wave*32 + mt*16 + l16;
                af[mt] = *(const bf8_t*)&As[r*64 + ((cg ^ (r&7))*8)];
            }
            #pragma unroll
            for (int nt = 0; nt < 4; ++nt) {
                int r = nt*16 + l16;
                bf8_t by = *(const bf8_t*)&Bys[r*64 + ((cg ^ (r&7))*8)];
                bf8_t bg = *(const bf8_t*)&Bgs[r*64 + ((cg ^ (r&7))*8)];
                #pragma unroll
                for (int mt = 0; mt < 2; ++mt) {
                    accy[mt][nt] = __builtin_amdgcn_mfma_f32_16x16x32_bf16(af[mt], by, accy[mt][nt], 0, 0, 0);
                    accg[mt][nt] = __builtin_amdgcn_mfma_f32_16x16x32_bf16(af[mt], bg, accg[mt][nt], 0, 0, 0);
                }
            }
        }
        __syncthreads();
    }

    #pragma unroll
    for (int mt = 0; mt < 2; ++mt) {
        #pragma unroll
        for (int r_ = 0; r_ < 4; ++r_) {
            int row = m0 + wave*32 + mt*16 + quad*4 + r_;
            size_t rb = (size_t)row * 2048;
            #pragma unroll
            for (int nt = 0; nt < 4; ++nt) {
                int col = n0 + nt*16 + l16;
                float y = accy[mt][nt][r_] + bias[col];
                float g = accg[mt][nt][r_] + bias[2048 + col];
                float t = tanhf(0.7978845608f*g*(1.f + 0.044715f*g*g));
                outp[rb + col] = f2b(y * 0.5f * g * (1.f + t));
            }
        }
    }
}

// ---------------- MFMA flash attention (R10 structure) ----------------
__global__ __launch_bounds__(512)
void attn_mfma_kernel(const bf16* __restrict__ Qm, const bf16* __restrict__ Km,
                      const bf16* __restrict__ VtG, bf16* __restrict__ Om,
                      int T, int vpitch)
{
    __shared__ __align__(16) unsigned short Ks[64*64];
    __shared__ __align__(16) unsigned short Vts[64*64];
    __shared__ __align__(16) unsigned short Ps[8][16*64];

    const int tid  = threadIdx.x;
    const int wave = tid >> 6, lane = tid & 63;
    const int l16  = lane & 15, quad = lane >> 4;
    const int b = blockIdx.z, h = blockIdx.y;
    const int qblk = blockIdx.x * 128;
    const int sr = tid >> 3, sc_ = tid & 7;   // staging: row 0..63, chunk 0..7

    bf8_t ones;
    #pragma unroll
    for (int j = 0; j < 8; ++j) ((unsigned short*)&ones)[j] = 0x3F80;

    // Q fragments (B-operand layout), pre-scaled by D^-0.5 * log2(e)
    bf8_t qf[2];
    {
        const bf16* qp = Qm + ((size_t)(b*SEQ + qblk + wave*16 + l16))*DIM + h*HD + quad*8;
        #pragma unroll
        for (int kc = 0; kc < 2; ++kc) {
            bf8_t v = *(const bf8_t*)(qp + kc*32);
            unsigned short* u = (unsigned short*)&v;
            unsigned int* w = (unsigned int*)&v;
            #pragma unroll
            for (int j = 0; j < 4; ++j) {
                float f0 = b2f(*(bf16*)&u[2*j])   * 0.1803368801f;
                float f1 = b2f(*(bf16*)&u[2*j+1]) * 0.1803368801f;
                w[j] = packbf2(f0, f1);
            }
            qf[kc] = v;
        }
    }

    f4_t o[4];
    #pragma unroll
    for (int dt = 0; dt < 4; ++dt) o[dt] = f4_t{0,0,0,0};
    f4_t lacc = {0,0,0,0};

    const bf16* Kbase = Km + (size_t)b*T*DIM + h*HD;
    const bf16* Vbase = VtG + ((size_t)((b*8 + h)*64 + sr))*vpitch;

    // prologue: load tile 0 into registers
    bf8_t kq, vq;
    kq = bf8_t{0,0,0,0,0,0,0,0};
    if (sr < T) kq = *(const bf8_t*)(Kbase + (size_t)sr*DIM + sc_*8);
    vq = *(const bf8_t*)(Vbase + sc_*8);

    const int ntiles = (T + 63) >> 6;
    for (int t0 = 0; t0 < ntiles; ++t0) {
        const int kb = t0 << 6;
        // ---- regs -> LDS (swizzled b128) ----
        *(bf8_t*)&Ks[sr*64 + ((sc_ ^ (sr&7))*8)]  = kq;
        *(bf8_t*)&Vts[sr*64 + ((sc_ ^ (sr&7))*8)] = vq;
        __syncthreads();
        // ---- prefetch next tile (overlaps compute) ----
        if (t0 + 1 < ntiles) {
            int gk = kb + 64 + sr;
            kq = bf8_t{0,0,0,0,0,0,0,0};
            if (gk < T) kq = *(const bf8_t*)(Kbase + (size_t)gk*DIM + sc_*8);
            vq = *(const bf8_t*)(Vbase + kb + 64 + sc_*8);
        }

        bf8_t kf[4][2], vf[4][2];
        #pragma unroll
        for (int t = 0; t < 4; ++t) {
            int r = t*16 + l16;
            #pragma unroll
            for (int kc = 0; kc < 2; ++kc) {
                int cg = kc*4 + quad;
                kf[t][kc] = *(const bf8_t*)&Ks[r*64 + ((cg ^ (r&7))*8)];
                vf[t][kc] = *(const bf8_t*)&Vts[r*64 + ((cg ^ (r&7))*8)];
            }
        }
        const bool tail = (kb + 64 > T);

        f4_t sc4[4];
        #pragma unroll
        for (int km = 0; km < 4; ++km) {
            f4_t c = {0,0,0,0};
            c = __builtin_amdgcn_mfma_f32_16x16x32_bf16(kf[km][0], qf[0], c, 0, 0, 0);
            c = __builtin_amdgcn_mfma_f32_16x16x32_bf16(kf[km][1], qf[1], c, 0, 0, 0);
            sc4[km] = c;
        }
        if (tail) {
            #pragma unroll
            for (int km = 0; km < 4; ++km)
                #pragma unroll
                for (int r = 0; r < 4; ++r)
                    if (kb + km*16 + quad*4 + r >= T) sc4[km][r] = -1e30f;
        }
        #pragma unroll
        for (int km = 0; km < 4; ++km) {
            uint2 w;
            w.x = packbf2(exp2f(sc4[km][0]), exp2f(sc4[km][1]));
            w.y = packbf2(exp2f(sc4[km][2]), exp2f(sc4[km][3]));
            int chunk = 2*km + (quad >> 1);
            int a = l16*64 + ((chunk ^ (l16 & 7))*8) + (quad & 1)*4;
            *(uint2*)&Ps[wave][a] = w;
        }
        #pragma unroll
        for (int kc = 0; kc < 2; ++kc) {
            int cg = kc*4 + quad;
            bf8_t pf = *(const bf8_t*)&Ps[wave][l16*64 + ((cg ^ (l16 & 7))*8)];
            lacc = __builtin_amdgcn_mfma_f32_16x16x32_bf16(ones, pf, lacc, 0, 0, 0);
            #pragma unroll
            for (int dt = 0; dt < 4; ++dt)
                o[dt] = __builtin_amdgcn_mfma_f32_16x16x32_bf16(vf[dt][kc], pf, o[dt], 0, 0, 0);
        }
        __syncthreads();
    }

    {
        float inv = 1.f / lacc[0];
        int tok = qblk + wave*16 + l16;
        size_t base = ((size_t)(b*SEQ + tok))*DIM + h*HD;
        #pragma unroll
        for (int dt = 0; dt < 4; ++dt) {
            uint2 w;
            w.x = packbf2(o[dt][0]*inv, o[dt][1]*inv);
            w.y = packbf2(o[dt][2]*inv, o[dt][3]*inv);
            *(uint2*)(Om + base + dt*16 + quad*4) = w;
        }
    }
}

extern "C" void kernel_launch(void* const* d_in, const int* in_sizes, int n_in,
                              void* d_out, int out_size, void* d_ws, size_t ws_size,
                              hipStream_t stream)
{
    (void)in_sizes; (void)n_in; (void)out_size; (void)ws_size;
    const float* x    = (const float*)d_in[0];
    const float* ctx  = (const float*)d_in[1];
    const float* ln1g = (const float*)d_in[2];
    const float* ln1b = (const float*)d_in[3];
    const float* wq1  = (const float*)d_in[4];
    const float* wk1  = (const float*)d_in[5];
    const float* wv1  = (const float*)d_in[6];
    const float* wo1  = (const float*)d_in[7];
    const float* bo1  = (const float*)d_in[8];
    const float* ln2g = (const float*)d_in[9];
    const float* ln2b = (const float*)d_in[10];
    const float* wq2  = (const float*)d_in[11];
    const float* wk2  = (const float*)d_in[12];
    const float* wv2  = (const float*)d_in[13];
    const float* wo2  = (const float*)d_in[14];
    const float* bo2  = (const float*)d_in[15];
    const float* ln3g = (const float*)d_in[16];
    const float* ln3b = (const float*)d_in[17];
    const float* gw   = (const float*)d_in[18];
    const float* gb   = (const float*)d_in[19];
    const float* ow   = (const float*)d_in[20];
    const float* ob   = (const float*)d_in[21];
    float* out = (float*)d_out;

    char* ws = (char*)d_ws;
    bf16* An  = (bf16*)(ws);
    bf16* Qb  = (bf16*)(ws + ((size_t)8<<20));
    bf16* Kb  = (bf16*)(ws + ((size_t)16<<20));
    bf16* Vb  = (bf16*)(ws + ((size_t)24<<20));
    bf16* Ob  = (bf16*)(ws + ((size_t)32<<20));
    bf16* FF  = Qb;
    float* Hf = out;
    bf16* WT  = (bf16*)(ws + ((size_t)40<<20));
    bf16* wq1T = WT + 0*262144, *wk1T = WT + 1*262144, *wv1T = WT + 2*262144, *wo1T = WT + 3*262144;
    bf16* wq2T = WT + 4*262144, *wk2T = WT + 5*262144, *wv2T = WT + 6*262144, *wo2T = WT + 7*262144;
    bf16* gwT  = (bf16*)(ws + ((size_t)44<<20));
    bf16* owT  = (bf16*)(ws + ((size_t)48<<20));
    bf16* ctxb = (bf16*)(ws + ((size_t)50<<20));
    bf16* VtG2 = (bf16*)(ws + ((size_t)50<<20) + ((size_t)512<<10));
    bf16* VtG  = (bf16*)(ws + ((size_t)52<<20));   // own region: written by QKV epilogue

    dim3 blk(256);
    dim3 blkA(512);

    // ---- fused weight prep (1 launch instead of 4) ----
    PrepArgs pa;
    pa.src8[0]=wq1; pa.src8[1]=wk1; pa.src8[2]=wv1; pa.src8[3]=wo1;
    pa.src8[4]=wq2; pa.src8[5]=wk2; pa.src8[6]=wv2; pa.src8[7]=wo2;
    pa.dst8[0]=wq1T; pa.dst8[1]=wk1T; pa.dst8[2]=wv1T; pa.dst8[3]=wo1T;
    pa.dst8[4]=wq2T; pa.dst8[5]=wk2T; pa.dst8[6]=wv2T; pa.dst8[7]=wo2T;
    pa.gw=gw; pa.gwT=gwT; pa.ow=ow; pa.owT=owT; pa.ctx=ctx; pa.ctxb=ctxb;
    prep_kernel<<<dim3(5428), blk, 0, stream>>>(pa);

    dim3 gLN(NTOK/4);
    dim3 gQKV(24, 64);        // N=1536 -> Qb, Kb, VtG (V written transposed)
    dim3 gG(8, 64);           // N=512
    dim3 gKVx(16, 2);         // N=1024, M=154 (guarded) -> Kb,Vb
    dim3 gGEGLU(32, 64);
    dim3 gATT(SEQ/128, NHEAD, BATCH);
    OutPtrs oQKV{{Qb, Kb, VtG}};
    OutPtrs oKVx{{Kb, Vb, nullptr}};
    OutPtrs oQ{{Qb, nullptr, nullptr}};
    OutPtrs oH{{Hf, nullptr, nullptr}};
    OutPtrs oOut{{out, nullptr, nullptr}};

    // ---- self-attention ----
    ln_kernel<<<gLN, blk, 0, stream>>>(x, ln1g, ln1b, An, NTOK);
    gemm_mfma_kernel<0,bf16,false,true><<<gQKV, blk, 0, stream>>>(An, wq1T, nullptr, nullptr, oQKV, NTOK, DIM);
    attn_mfma_kernel<<<gATT, blkA, 0, stream>>>(Qb, Kb, VtG, Ob, SEQ, SEQ);
    gemm_mfma_kernel<1,float,false,false><<<gG, blk, 0, stream>>>(Ob, wo1T, bo1, x, oH, NTOK, DIM);

    // ---- cross-attention ----
    ln_kernel<<<gLN, blk, 0, stream>>>(Hf, ln2g, ln2b, An, NTOK);
    gemm_mfma_kernel<0,bf16,false,false><<<gG, blk, 0, stream>>>(An, wq2T, nullptr, nullptr, oQ, NTOK, DIM);
    gemm_mfma_kernel<0,bf16,true,false><<<gKVx, blk, 0, stream>>>(ctxb, wk2T, nullptr, nullptr, oKVx, NCTX, DIM);
    v_transpose_kernel<<<dim3(2, NHEAD, BATCH), blk, 0, stream>>>(Vb, VtG2, CTXLEN, 128);
    attn_mfma_kernel<<<gATT, blkA, 0, stream>>>(Qb, Kb, VtG2, Ob, CTXLEN, 128);
    gemm_mfma_kernel<1,float,false,false><<<gG, blk, 0, stream>>>(Ob, wo2T, bo2, Hf, oH, NTOK, DIM);

    // ---- GEGLU FFN + output projection ----
    ln_kernel<<<gLN, blk, 0, stream>>>(Hf, ln3g, ln3b, An, NTOK);
    geglu_mfma_kernel<<<gGEGLU, blk, 0, stream>>>(An, gwT, gb, FF);
    gemm_mfma_kernel<1,float,false,false><<<gG, blk, 0, stream>>>(FF, owT, ob, Hf, oOut, NTOK, 2048);
}